// Round 1
// baseline (231.330 us; speedup 1.0000x reference)
//
#include <hip/hip_runtime.h>

// LowRankRotatedSpaceIntervention — fused single-pass kernel.
// out[b,:] = base[b,:] + (mask_b . ((source[b,:]-base[b,:]) @ W)) @ W^T
// B=16384, D=4096, R=64, 8 partitions of 8, 4 selected per row.
//
// Plan: 1024 blocks x 256 threads; each block owns 16 rows.
//  Phase 1: 4 waves each stream a K-quarter of base/source (fp32),
//           compute d=src-base in bf16 into per-wave LDS stage, ALSO park
//           base (bf16) in a 16x4096 LDS tile; MFMA 16x16x32 accumulates
//           r_partial[16][64] per wave.  Reduce 4 partials, apply per-row
//           partition mask -> rm_bf16[16][64] in LDS.
//  Phase 2: 4 waves each own a 1024-col quarter: C = rm @ W^T via MFMA,
//           add base from LDS, coalesced float4 stores.
// HBM traffic = base + source + out = 768 MB (W lives in L2, ~1MB).

#define D_DIM 4096
#define R_DIM 64
#define BM    16
#define KC    64
#define KW    1024

typedef short bf16vec8 __attribute__((ext_vector_type(8)));
typedef float f32x4v  __attribute__((ext_vector_type(4)));

// LDS layout (bytes)
#define OFF_BASE    0        // [16][4096] bf16 = 131072
#define OFF_STAGE   131072   // 4 waves * [16][64] bf16 (2048 each) = 8192
#define OFF_SCRATCH 139264   // 4 * 4096 B (f32 partials, later C-buf) = 16384
#define OFF_RM      155648   // [16][64] bf16 = 2048
#define SMEM_BYTES  157696   // <= 160 KiB

__device__ __forceinline__ unsigned int f2bf_u(float f) {
  unsigned int u = __builtin_bit_cast(unsigned int, f);
  return (u + 0x7fffu + ((u >> 16) & 1u)) >> 16;   // RNE
}
__device__ __forceinline__ unsigned int pack2bf(float a, float b) {
  return f2bf_u(a) | (f2bf_u(b) << 16);
}
__device__ __forceinline__ float bfbits2f(unsigned short s) {
  unsigned int u = ((unsigned int)s) << 16;
  return __builtin_bit_cast(float, u);
}

__global__ __launch_bounds__(256)
void lrri_prep(const float* __restrict__ W, unsigned short* __restrict__ Wt,
               unsigned short* __restrict__ Wb) {
  const int idx = blockIdx.x * blockDim.x + threadIdx.x;   // 0..65535
  const int k = idx >> 4;
  const int j = (idx & 15) * 4;
  float4 w = *(const float4*)(W + (size_t)k * R_DIM + j);
  ushort4 p;
  p.x = (unsigned short)f2bf_u(w.x);
  p.y = (unsigned short)f2bf_u(w.y);
  p.z = (unsigned short)f2bf_u(w.z);
  p.w = (unsigned short)f2bf_u(w.w);
  *(ushort4*)(Wb + (size_t)k * R_DIM + j) = p;     // [4096][64] bf16
  Wt[(size_t)(j + 0) * D_DIM + k] = p.x;           // [64][4096] bf16
  Wt[(size_t)(j + 1) * D_DIM + k] = p.y;
  Wt[(size_t)(j + 2) * D_DIM + k] = p.z;
  Wt[(size_t)(j + 3) * D_DIM + k] = p.w;
}

template<bool USE_WS>
__global__ __launch_bounds__(256)
void lrri_fused(const float* __restrict__ base, const float* __restrict__ srcp,
                const float* __restrict__ W, const int* __restrict__ subs,
                const unsigned short* __restrict__ Wt_bf,   // [64][4096]
                const unsigned short* __restrict__ Wb_bf,   // [4096][64]
                float* __restrict__ out)
{
  __shared__ __align__(16) unsigned char smem[SMEM_BYTES];
  const int tid  = threadIdx.x;
  const int wave = tid >> 6;
  const int lane = tid & 63;
  const int l4   = lane & 15;
  const int g    = lane >> 4;
  const long rowbase = (long)blockIdx.x * BM;

  unsigned short* stage   = (unsigned short*)(smem + OFF_STAGE + wave * 2048);
  unsigned short* baseLds = (unsigned short*)(smem + OFF_BASE);

  // ---------------- Phase 1: r = (src-base) @ W over this wave's K range ---
  f32x4v acc[4];
  #pragma unroll
  for (int t = 0; t < 4; ++t) acc[t] = (f32x4v){0.f, 0.f, 0.f, 0.f};

  const int kw0 = wave * KW;
  #pragma unroll 1
  for (int c = 0; c < KW / KC; ++c) {
    const int kbase = kw0 + c * KC;
    float4 b4[4], s4[4];
    #pragma unroll
    for (int i = 0; i < 4; ++i) {               // 4 rows x 256B contiguous segs
      const int r = g + i * 4;
      const long off = (rowbase + r) * D_DIM + kbase + l4 * 4;
      b4[i] = *(const float4*)(base + off);
      s4[i] = *(const float4*)(srcp + off);
    }
    #pragma unroll
    for (int i = 0; i < 4; ++i) {
      const int r = g + i * 4;
      uint2 dp, bp;
      dp.x = pack2bf(s4[i].x - b4[i].x, s4[i].y - b4[i].y);
      dp.y = pack2bf(s4[i].z - b4[i].z, s4[i].w - b4[i].w);
      *(uint2*)((unsigned char*)stage + r * 128 + l4 * 8) = dp;
      bp.x = pack2bf(b4[i].x, b4[i].y);
      bp.y = pack2bf(b4[i].z, b4[i].w);
      *(uint2*)((unsigned char*)baseLds + r * 8192 + (kbase + l4 * 4) * 2) = bp;
    }
    // A fragments: row = l4, k = s*32 + g*8 + e  (same k-map used for B)
    uint4 af[2];
    #pragma unroll
    for (int s = 0; s < 2; ++s)
      af[s] = *(const uint4*)((unsigned char*)stage + l4 * 128 + s * 64 + g * 16);
    #pragma unroll
    for (int t = 0; t < 4; ++t) {
      #pragma unroll
      for (int s = 0; s < 2; ++s) {
        uint4 bfrag;
        if (USE_WS) {
          bfrag = *(const uint4*)(Wt_bf + (size_t)(t * 16 + l4) * D_DIM +
                                  kbase + s * 32 + g * 8);
        } else {
          unsigned int p[4];
          #pragma unroll
          for (int e2 = 0; e2 < 4; ++e2) {
            float wa = W[(size_t)(kbase + s * 32 + g * 8 + e2 * 2    ) * R_DIM + t * 16 + l4];
            float wb = W[(size_t)(kbase + s * 32 + g * 8 + e2 * 2 + 1) * R_DIM + t * 16 + l4];
            p[e2] = pack2bf(wa, wb);
          }
          bfrag.x = p[0]; bfrag.y = p[1]; bfrag.z = p[2]; bfrag.w = p[3];
        }
        acc[t] = __builtin_amdgcn_mfma_f32_16x16x32_bf16(
            __builtin_bit_cast(bf16vec8, af[s]),
            __builtin_bit_cast(bf16vec8, bfrag), acc[t], 0, 0, 0);
      }
    }
  }
  // write per-wave partials: C/D layout row=(g*4+i), col=l4 within j-tile t
  {
    float* part = (float*)(smem + OFF_SCRATCH + wave * 4096);
    #pragma unroll
    for (int t = 0; t < 4; ++t)
      #pragma unroll
      for (int i = 0; i < 4; ++i)
        part[(g * 4 + i) * 64 + t * 16 + l4] = acc[t][i];
  }
  __syncthreads();

  // ---------------- Reduce partials + per-row partition mask --------------
  {
    const int row = tid >> 4, jg = tid & 15;
    const float* p0 = (const float*)(smem + OFF_SCRATCH);
    int4 sb = *(const int4*)(subs + (rowbase + row) * 4);
    unsigned mbits = (1u << sb.x) | (1u << sb.y) | (1u << sb.z) | (1u << sb.w);
    unsigned short vals[4];
    #pragma unroll
    for (int jj = 0; jj < 4; ++jj) {
      const int j = jg * 4 + jj;
      float sum = p0[row * 64 + j] + p0[1024 + row * 64 + j] +
                  p0[2048 + row * 64 + j] + p0[3072 + row * 64 + j];
      vals[jj] = ((mbits >> (j >> 3)) & 1u) ? (unsigned short)f2bf_u(sum)
                                            : (unsigned short)0;
    }
    unsigned short* rm = (unsigned short*)(smem + OFF_RM);
    uint2 pk;
    pk.x = (unsigned)vals[0] | ((unsigned)vals[1] << 16);
    pk.y = (unsigned)vals[2] | ((unsigned)vals[3] << 16);
    *(uint2*)(rm + row * 64 + jg * 4) = pk;
  }
  __syncthreads();

  // ---------------- Phase 2: out = baseLds + rm @ W^T ---------------------
  uint4 a2[2];
  {
    const unsigned short* rm = (const unsigned short*)(smem + OFF_RM);
    #pragma unroll
    for (int s = 0; s < 2; ++s)
      a2[s] = *(const uint4*)((const unsigned char*)rm + l4 * 128 + s * 64 + g * 16);
  }
  float* cbuf = (float*)(smem + OFF_SCRATCH + wave * 4096);
  #pragma unroll 1
  for (int grp = 0; grp < 16; ++grp) {
    const int cbase = wave * 1024 + grp * 64;
    #pragma unroll
    for (int t = 0; t < 4; ++t) {
      f32x4v a = (f32x4v){0.f, 0.f, 0.f, 0.f};
      #pragma unroll
      for (int s = 0; s < 2; ++s) {
        uint4 bfrag;  // B[kk=j][n=col] = W[col][j]; per-lane 8 consecutive j
        if (USE_WS) {
          bfrag = *(const uint4*)(Wb_bf + (size_t)(cbase + t * 16 + l4) * R_DIM +
                                  s * 32 + g * 8);
        } else {
          const float* wp = W + (size_t)(cbase + t * 16 + l4) * R_DIM + s * 32 + g * 8;
          float4 wa = *(const float4*)(wp);
          float4 wb = *(const float4*)(wp + 4);
          bfrag.x = pack2bf(wa.x, wa.y); bfrag.y = pack2bf(wa.z, wa.w);
          bfrag.z = pack2bf(wb.x, wb.y); bfrag.w = pack2bf(wb.z, wb.w);
        }
        a = __builtin_amdgcn_mfma_f32_16x16x32_bf16(
            __builtin_bit_cast(bf16vec8, a2[s]),
            __builtin_bit_cast(bf16vec8, bfrag), a, 0, 0, 0);
      }
      #pragma unroll
      for (int i = 0; i < 4; ++i)
        cbuf[(g * 4 + i) * 64 + t * 16 + l4] = a[i];
    }
    // transpose via LDS -> coalesced float4 stores (4 rows x 256B per instr)
    #pragma unroll
    for (int s2 = 0; s2 < 4; ++s2) {
      const int r = g + s2 * 4;
      f32x4v cv = *(const f32x4v*)(cbuf + r * 64 + l4 * 4);
      ushort4 bb = *(const ushort4*)((const unsigned char*)baseLds + r * 8192 +
                                     (cbase + l4 * 4) * 2);
      float4 o;
      o.x = cv[0] + bfbits2f(bb.x);
      o.y = cv[1] + bfbits2f(bb.y);
      o.z = cv[2] + bfbits2f(bb.z);
      o.w = cv[3] + bfbits2f(bb.w);
      *(float4*)(out + (rowbase + r) * D_DIM + cbase + l4 * 4) = o;
    }
  }
}

extern "C" void kernel_launch(void* const* d_in, const int* in_sizes, int n_in,
                              void* d_out, int out_size, void* d_ws, size_t ws_size,
                              hipStream_t stream) {
  const float* base = (const float*)d_in[0];
  const float* srcp = (const float*)d_in[1];
  const float* W    = (const float*)d_in[2];
  const int*   subs = (const int*)d_in[3];
  float* out = (float*)d_out;

  const int nblocks = 16384 / BM;   // 1024
  const size_t wbytes = (size_t)2 * R_DIM * D_DIM * sizeof(unsigned short); // 1 MB
  if (d_ws && ws_size >= wbytes) {
    unsigned short* Wt = (unsigned short*)d_ws;          // [64][4096] bf16
    unsigned short* Wb = Wt + (size_t)R_DIM * D_DIM;     // [4096][64] bf16
    lrri_prep<<<256, 256, 0, stream>>>(W, Wt, Wb);
    lrri_fused<true><<<nblocks, 256, 0, stream>>>(base, srcp, W, subs, Wt, Wb, out);
  } else {
    lrri_fused<false><<<nblocks, 256, 0, stream>>>(base, srcp, W, subs, nullptr, nullptr, out);
  }
}